// Round 2
// baseline (345.209 us; speedup 1.0000x reference)
//
#include <hip/hip_runtime.h>
#include <math.h>

#define B_DIM 8
#define T_DIM 8192
#define D_DIM 2048
#define N_ROWS (B_DIM * T_DIM)
#define K_SEL 2048 /* max(1, int(T_DIM * 0.25)) */
#define EPS_D 1e-10

// ---------------------------------------------------------------------------
// Kernel 1: per-row squared-norm reductions.  One 256-thread block per (b,t)
// row of D=2048 floats.  float4 loads (16B/lane), f32 fma partials per thread
// (8 elements -> negligible rounding), double cross-thread reduction.
// ---------------------------------------------------------------------------
__global__ __launch_bounds__(256) void row_reduce_kernel(
    const float* __restrict__ a, const float* __restrict__ p,
    double* __restrict__ dst, double* __restrict__ dch) {
  const int row = blockIdx.x;
  const int tid = threadIdx.x;
  const float4* a4 = reinterpret_cast<const float4*>(a) + (size_t)row * (D_DIM / 4);
  const float4* p4 = reinterpret_cast<const float4*>(p) + (size_t)row * (D_DIM / 4);
  float s_st = 0.f, s_ch = 0.f;
#pragma unroll
  for (int it = 0; it < D_DIM / 4 / 256; ++it) {
    float4 av = a4[tid + it * 256];
    float4 pv = p4[tid + it * 256];
    s_st = fmaf(av.x, av.x, s_st);
    s_st = fmaf(av.y, av.y, s_st);
    s_st = fmaf(av.z, av.z, s_st);
    s_st = fmaf(av.w, av.w, s_st);
    float dx = av.x - pv.x, dy = av.y - pv.y, dz = av.z - pv.z, dw = av.w - pv.w;
    s_ch = fmaf(dx, dx, s_ch);
    s_ch = fmaf(dy, dy, s_ch);
    s_ch = fmaf(dz, dz, s_ch);
    s_ch = fmaf(dw, dw, s_ch);
  }
  double d_st = (double)s_st, d_ch = (double)s_ch;
#pragma unroll
  for (int off = 32; off > 0; off >>= 1) {
    d_st += __shfl_down(d_st, off);
    d_ch += __shfl_down(d_ch, off);
  }
  __shared__ double l_st[4], l_ch[4];
  const int wid = tid >> 6, lane = tid & 63;
  if (lane == 0) { l_st[wid] = d_st; l_ch[wid] = d_ch; }
  __syncthreads();
  if (tid == 0) {
    double t_st = l_st[0] + l_st[1] + l_st[2] + l_st[3];
    double t_ch = l_ch[0] + l_ch[1] + l_ch[2] + l_ch[3];
    dst[row] = t_st * (1.0 / D_DIM);
    dch[row] = t_ch * (1.0 / D_DIM);
  }
}

// ---------------------------------------------------------------------------
// Kernel 2: global mean of D_st (65536 doubles -> 1 double).  Single block.
// ---------------------------------------------------------------------------
__global__ __launch_bounds__(1024) void mean_kernel(const double* __restrict__ dst,
                                                    double* __restrict__ ma_out) {
  const int tid = threadIdx.x;
  double s = 0.0;
  for (int i = tid; i < N_ROWS; i += 1024) s += dst[i];
#pragma unroll
  for (int off = 32; off > 0; off >>= 1) s += __shfl_down(s, off);
  __shared__ double l[16];
  if ((tid & 63) == 0) l[tid >> 6] = s;
  __syncthreads();
  if (tid == 0) {
    double t = 0.0;
    for (int w = 0; w < 16; ++w) t += l[w];
    *ma_out = t * (1.0 / N_ROWS);
  }
}

// ---------------------------------------------------------------------------
// Kernel 3: gate computation (double precision) + exact top-k mask per batch
// row.  Keys = double bit-pattern of g (positive -> monotone as u64) with the
// low 13 mantissa bits replaced by (T-1-i): all keys distinct, lower index
// wins ties (matches jax.lax.top_k), so "key >= kth largest key" selects
// exactly K elements — no equality-counting machinery needed.
// Bitonic sort of 8192 u64 keys in exactly 64 KiB of LDS.
// ---------------------------------------------------------------------------
__device__ __forceinline__ double compute_g(double d_st, double d_ch, double ma,
                                            double log_oce, double mcu,
                                            double bce, double bcu) {
  double CE = d_st - (d_ch - log_oce);
  double CU = d_st - mcu * ma;
  double sce = 1.0 / (1.0 + exp(-bce * CE));
  double scu = 1.0 / (1.0 + exp(-bcu * CU));
  return sce + scu - sce * scu;
}

__global__ __launch_bounds__(1024) void topk_kernel(
    const double* __restrict__ dst, const double* __restrict__ dch,
    const double* __restrict__ ma_p,
    const float* __restrict__ o_ce_p, const float* __restrict__ m_cu_p,
    const float* __restrict__ b_ce_p, const float* __restrict__ b_cu_p,
    float* __restrict__ g_out, float* __restrict__ mask_out) {
  __shared__ unsigned long long s[T_DIM]; // exactly 64 KiB — sole LDS use
  const int b = blockIdx.x;
  const int tid = threadIdx.x;
  const double ma = *ma_p;
  const double log_oce = log((double)(*o_ce_p) + EPS_D);
  const double mcu = (double)(*m_cu_p);
  double x = (double)(*b_ce_p);
  const double bce = (x > 30.0) ? x : log1p(exp(x)); // softplus
  x = (double)(*b_cu_p);
  const double bcu = (x > 30.0) ? x : log1p(exp(x));
  const double* dst_row = dst + (size_t)b * T_DIM;
  const double* dch_row = dch + (size_t)b * T_DIM;

  unsigned long long key_r[T_DIM / 1024];
#pragma unroll
  for (int c = 0; c < T_DIM / 1024; ++c) {
    int i = c * 1024 + tid;
    double g = compute_g(dst_row[i], dch_row[i], ma, log_oce, mcu, bce, bcu);
    g_out[(size_t)b * T_DIM + i] = (float)g;
    unsigned long long ub = (unsigned long long)__double_as_longlong(g);
    unsigned long long key =
        (ub & ~0x1FFFULL) | (unsigned long long)(T_DIM - 1 - i);
    key_r[c] = key;
    s[i] = key;
  }

  // bitonic sort ascending over 8192 keys
  for (unsigned kk = 2; kk <= (unsigned)T_DIM; kk <<= 1) {
    for (unsigned j = kk >> 1; j > 0; j >>= 1) {
      __syncthreads();
      for (unsigned i = tid; i < (unsigned)T_DIM; i += 1024) {
        unsigned ixj = i ^ j;
        if (ixj > i) {
          unsigned long long xi = s[i], xj = s[ixj];
          bool up = ((i & kk) == 0);
          if (up ? (xi > xj) : (xi < xj)) {
            s[i] = xj;
            s[ixj] = xi;
          }
        }
      }
    }
  }
  __syncthreads();
  const unsigned long long thresh = s[T_DIM - K_SEL]; // k-th largest key

#pragma unroll
  for (int c = 0; c < T_DIM / 1024; ++c) {
    int i = c * 1024 + tid;
    mask_out[(size_t)b * T_DIM + i] = (key_r[c] >= thresh) ? 1.0f : 0.0f;
  }
}

extern "C" void kernel_launch(void* const* d_in, const int* in_sizes, int n_in,
                              void* d_out, int out_size, void* d_ws, size_t ws_size,
                              hipStream_t stream) {
  const float* a = (const float*)d_in[0];     // actual_residual  [B,T,D]
  const float* p = (const float*)d_in[1];     // predicted_residual [B,T,D]
  const float* o_ce = (const float*)d_in[2];  // scalars
  const float* m_cu = (const float*)d_in[3];
  const float* b_ce = (const float*)d_in[4];
  const float* b_cu = (const float*)d_in[5];
  float* out = (float*)d_out; // [0,65536): g_continuous, [65536,131072): mask

  // workspace layout (1 MiB + 8 B): D_st[65536] | D_ch[65536] | ma[1]
  double* dst = (double*)d_ws;
  double* dch = dst + N_ROWS;
  double* ma = dch + N_ROWS;

  row_reduce_kernel<<<N_ROWS, 256, 0, stream>>>(a, p, dst, dch);
  mean_kernel<<<1, 1024, 0, stream>>>(dst, ma);
  topk_kernel<<<B_DIM, 1024, 0, stream>>>(dst, dch, ma, o_ce, m_cu, b_ce, b_cu,
                                          out, out + N_ROWS);
}

// Round 3
// 214.583 us; speedup vs baseline: 1.6087x; 1.6087x over previous
//
#include <hip/hip_runtime.h>
#include <math.h>

#define B_DIM 8
#define T_DIM 8192
#define D_DIM 2048
#define N_ROWS (B_DIM * T_DIM)
#define K_SEL 2048 /* max(1, int(T_DIM * 0.25)) */
#define EPS_D 1e-10

// ---------------------------------------------------------------------------
// Kernel 1: per-row squared-norm reductions.  One WAVE per (b,t) row
// (4 rows per 256-thread block — no LDS, no barriers).  float4 loads
// (16B/lane, 1KB/instr/wave), per-float4 f32 square-sum folded into a
// per-lane f64 accumulator, f64 wave shuffle reduce.
// ---------------------------------------------------------------------------
__global__ __launch_bounds__(256) void row_reduce_kernel(
    const float* __restrict__ a, const float* __restrict__ p,
    double* __restrict__ dst, double* __restrict__ dch) {
  const int tid = threadIdx.x;
  const int lane = tid & 63;
  const int row = blockIdx.x * 4 + (tid >> 6);
  const float4* a4 = reinterpret_cast<const float4*>(a) + (size_t)row * (D_DIM / 4);
  const float4* p4 = reinterpret_cast<const float4*>(p) + (size_t)row * (D_DIM / 4);
  double d_st = 0.0, d_ch = 0.0;
#pragma unroll
  for (int it = 0; it < D_DIM / 4 / 64; ++it) {
    float4 av = a4[it * 64 + lane];
    float4 pv = p4[it * 64 + lane];
    float s = av.x * av.x;
    s = fmaf(av.y, av.y, s);
    s = fmaf(av.z, av.z, s);
    s = fmaf(av.w, av.w, s);
    float dx = av.x - pv.x, dy = av.y - pv.y, dz = av.z - pv.z, dw = av.w - pv.w;
    float c = dx * dx;
    c = fmaf(dy, dy, c);
    c = fmaf(dz, dz, c);
    c = fmaf(dw, dw, c);
    d_st += (double)s;
    d_ch += (double)c;
  }
#pragma unroll
  for (int off = 32; off > 0; off >>= 1) {
    d_st += __shfl_down(d_st, off);
    d_ch += __shfl_down(d_ch, off);
  }
  if (lane == 0) {
    dst[row] = d_st * (1.0 / D_DIM);
    dch[row] = d_ch * (1.0 / D_DIM);
  }
}

// ---------------------------------------------------------------------------
// Kernel 2: per-batch-row gate (f64) + exact top-k mask via MSB-first
// radix-select on distinct u64 keys.
//   key = bits(g) with low 13 mantissa bits replaced by (T-1-i):
//   g>0 so the double bit pattern is order-preserving as u64; keys are all
//   distinct and lower index wins ties (matches jax.lax.top_k), so
//   "key >= kth-largest-key" selects exactly K elements.
// The global mean of D_st is recomputed redundantly (identical fixed-order
// tree) in every block — deterministic, drops the separate mean kernel.
// Radix-select: skip bytes common to min/max, then 8-bit digit passes with a
// 256-bin LDS histogram; early-exit when the selected bin holds 1 candidate.
// ---------------------------------------------------------------------------
__global__ __launch_bounds__(1024) void topk_kernel(
    const double* __restrict__ dst, const double* __restrict__ dch,
    const float* __restrict__ o_ce_p, const float* __restrict__ m_cu_p,
    const float* __restrict__ b_ce_p, const float* __restrict__ b_cu_p,
    float* __restrict__ g_out, float* __restrict__ mask_out) {
  const int b = blockIdx.x;
  const int tid = threadIdx.x;
  const int lane = tid & 63;
  const int wid = tid >> 6;

  __shared__ double wsum[16];
  __shared__ unsigned long long wmin[16], wmax[16];
  __shared__ unsigned hist[256];
  __shared__ unsigned bc_d, bc_cnt, bc_r;
  __shared__ unsigned long long bc_key;

  // ---- global mean of D_st (deterministic, identical in all blocks) ----
  double s = 0.0;
  for (int j = 0; j < N_ROWS / 1024; ++j) s += dst[j * 1024 + tid];
#pragma unroll
  for (int off = 32; off > 0; off >>= 1) s += __shfl_down(s, off);
  if (lane == 0) wsum[wid] = s;
  __syncthreads();
  double tot = 0.0;
#pragma unroll
  for (int w = 0; w < 16; ++w) tot += wsum[w];
  const double ma = tot * (1.0 / N_ROWS);

  // ---- scalars (f64) ----
  const double log_oce = log((double)(*o_ce_p) + EPS_D);
  const double mcu = (double)(*m_cu_p);
  double x = (double)(*b_ce_p);
  const double bce = (x > 30.0) ? x : log1p(exp(x)); // softplus
  x = (double)(*b_cu_p);
  const double bcu = (x > 30.0) ? x : log1p(exp(x));

  // ---- gate + keys (8 per thread, registers only) ----
  const double* dr = dst + (size_t)b * T_DIM;
  const double* cr = dch + (size_t)b * T_DIM;
  unsigned long long key[8];
  unsigned long long kmin = ~0ULL, kmax = 0ULL;
#pragma unroll
  for (int c = 0; c < 8; ++c) {
    const int i = c * 1024 + tid;
    const double CE = dr[i] - (cr[i] - log_oce);
    const double CU = dr[i] - mcu * ma;
    const double sce = 1.0 / (1.0 + exp(-bce * CE));
    const double scu = 1.0 / (1.0 + exp(-bcu * CU));
    const double g = sce + scu - sce * scu;
    g_out[(size_t)b * T_DIM + i] = (float)g;
    const unsigned long long ub = (unsigned long long)__double_as_longlong(g);
    const unsigned long long k =
        (ub & ~0x1FFFULL) | (unsigned long long)(T_DIM - 1 - i);
    key[c] = k;
    kmin = (k < kmin) ? k : kmin;
    kmax = (k > kmax) ? k : kmax;
  }
  // block min/max (uniform result in every thread)
#pragma unroll
  for (int off = 32; off > 0; off >>= 1) {
    unsigned long long tmin = __shfl_down(kmin, off);
    unsigned long long tmax = __shfl_down(kmax, off);
    kmin = (tmin < kmin) ? tmin : kmin;
    kmax = (tmax > kmax) ? tmax : kmax;
  }
  if (lane == 0) { wmin[wid] = kmin; wmax[wid] = kmax; }
  __syncthreads();
  kmin = wmin[0];
  kmax = wmax[0];
#pragma unroll
  for (int w = 1; w < 16; ++w) {
    kmin = (wmin[w] < kmin) ? wmin[w] : kmin;
    kmax = (wmax[w] > kmax) ? wmax[w] : kmax;
  }

  // ---- radix select: k-th largest of 8192 distinct keys ----
  const unsigned long long diff = kmin ^ kmax; // != 0 (index bits distinct)
  const int hb = 63 - __clzll(diff);
  const int bi0 = hb >> 3; // first informative byte
  const int sh_top = (bi0 + 1) * 8;
  unsigned long long pmask = (sh_top >= 64) ? 0ULL : (~0ULL << sh_top);
  unsigned long long prefix = kmin & pmask;
  unsigned r = K_SEL; // 1-based rank from the top within candidates
  unsigned long long thresh = 0ULL;
  bool found = false;

  for (int bi = bi0; bi >= 0 && !found; --bi) {
    const int sh = bi * 8;
    if (tid < 256) hist[tid] = 0;
    __syncthreads();
#pragma unroll
    for (int c = 0; c < 8; ++c)
      if ((key[c] & pmask) == prefix)
        atomicAdd(&hist[(unsigned)((key[c] >> sh) & 0xFF)], 1u);
    __syncthreads();
    if (wid == 0) {
      // lane holds bins {lane, 64+lane, 128+lane, 192+lane}
      unsigned h[4], S[4];
#pragma unroll
      for (int j = 0; j < 4; ++j) {
        h[j] = hist[j * 64 + lane];
        unsigned t = h[j];
#pragma unroll
        for (int off = 32; off > 0; off >>= 1) t += __shfl_xor(t, off);
        S[j] = t; // chunk total, uniform across wave
      }
      // pick chunk scanning from the top
      int J;
      unsigned above;
      if (S[3] >= r) { J = 3; above = 0; }
      else if (S[3] + S[2] >= r) { J = 2; above = S[3]; }
      else if (S[3] + S[2] + S[1] >= r) { J = 1; above = S[3] + S[2]; }
      else { J = 0; above = S[3] + S[2] + S[1]; }
      const unsigned r_in = r - above;
      // inclusive suffix-sum over the 64 bins of chunk J
      unsigned v = h[J];
#pragma unroll
      for (int off = 1; off < 64; off <<= 1) {
        unsigned o = __shfl_down(v, off);
        if (lane + off < 64) v += o;
      }
      unsigned sufnext = __shfl_down(v, 1);
      if (lane == 63) sufnext = 0;
      if (v >= r_in && sufnext < r_in) { // exactly one lane
        bc_d = (unsigned)(J * 64 + lane);
        bc_cnt = h[J];
        bc_r = r_in - sufnext;
      }
    }
    __syncthreads();
    const unsigned d = bc_d;
    const unsigned cnt = bc_cnt;
    r = bc_r;
    prefix |= (unsigned long long)d << sh;
    pmask |= 0xFFULL << sh;
    if (cnt == 1) { // unique candidate == the k-th largest key
#pragma unroll
      for (int c = 0; c < 8; ++c)
        if ((key[c] & pmask) == prefix) bc_key = key[c];
      __syncthreads();
      thresh = bc_key;
      found = true;
    }
  }
  if (!found) thresh = prefix; // unreachable (keys distinct), safety net

  // ---- binary mask ----
#pragma unroll
  for (int c = 0; c < 8; ++c) {
    const int i = c * 1024 + tid;
    mask_out[(size_t)b * T_DIM + i] = (key[c] >= thresh) ? 1.0f : 0.0f;
  }
}

extern "C" void kernel_launch(void* const* d_in, const int* in_sizes, int n_in,
                              void* d_out, int out_size, void* d_ws, size_t ws_size,
                              hipStream_t stream) {
  const float* a = (const float*)d_in[0];    // actual_residual   [B,T,D]
  const float* p = (const float*)d_in[1];    // predicted_residual [B,T,D]
  const float* o_ce = (const float*)d_in[2]; // scalars
  const float* m_cu = (const float*)d_in[3];
  const float* b_ce = (const float*)d_in[4];
  const float* b_cu = (const float*)d_in[5];
  float* out = (float*)d_out; // [0,65536): g_continuous, [65536,131072): mask

  // workspace: D_st[65536] | D_ch[65536]  (1 MiB, rewritten fully every call)
  double* dst = (double*)d_ws;
  double* dch = dst + N_ROWS;

  row_reduce_kernel<<<N_ROWS / 4, 256, 0, stream>>>(a, p, dst, dch);
  topk_kernel<<<B_DIM, 1024, 0, stream>>>(dst, dch, o_ce, m_cu, b_ce, b_cu,
                                          out, out + N_ROWS);
}

// Round 5
// 193.408 us; speedup vs baseline: 1.7849x; 1.1095x over previous
//
#include <hip/hip_runtime.h>
#include <math.h>

#define B_DIM 8
#define T_DIM 8192
#define D_DIM 2048
#define N_ROWS (B_DIM * T_DIM)
#define K_SEL 2048 /* max(1, int(T_DIM * 0.25)) */
#define EPS_D 1e-10

typedef float f32x4 __attribute__((ext_vector_type(4))); // clang vector: valid
                                                         // for nontemporal_load

// ---------------------------------------------------------------------------
// Kernel 1: per-row squared-norm reductions.  One WAVE per (b,t) row
// (4 rows per 256-thread block — no LDS, no barriers).
// v5: ALL 16 float4 loads (a-row + p-row) issued before any math so the
// maximum number of loads is in flight per wave.  Nontemporal hint: 1 GB
// streaming reads can never live in the 32 MiB L2.  Math order is
// bit-identical to round 3 (f32 chain per float4 -> f64 accumulate).
// ---------------------------------------------------------------------------
__global__ __launch_bounds__(256) void row_reduce_kernel(
    const float* __restrict__ a, const float* __restrict__ p,
    double* __restrict__ dst, double* __restrict__ dch) {
  const int tid = threadIdx.x;
  const int lane = tid & 63;
  const int row = blockIdx.x * 4 + (tid >> 6);
  const f32x4* a4 = reinterpret_cast<const f32x4*>(a) + (size_t)row * (D_DIM / 4);
  const f32x4* p4 = reinterpret_cast<const f32x4*>(p) + (size_t)row * (D_DIM / 4);

  f32x4 av[8], pv[8];
#pragma unroll
  for (int it = 0; it < 8; ++it)
    av[it] = __builtin_nontemporal_load(&a4[it * 64 + lane]);
#pragma unroll
  for (int it = 0; it < 8; ++it)
    pv[it] = __builtin_nontemporal_load(&p4[it * 64 + lane]);

  double d_st = 0.0, d_ch = 0.0;
#pragma unroll
  for (int it = 0; it < 8; ++it) {
    float s = av[it].x * av[it].x;
    s = fmaf(av[it].y, av[it].y, s);
    s = fmaf(av[it].z, av[it].z, s);
    s = fmaf(av[it].w, av[it].w, s);
    float dx = av[it].x - pv[it].x, dy = av[it].y - pv[it].y;
    float dz = av[it].z - pv[it].z, dw = av[it].w - pv[it].w;
    float c = dx * dx;
    c = fmaf(dy, dy, c);
    c = fmaf(dz, dz, c);
    c = fmaf(dw, dw, c);
    d_st += (double)s;
    d_ch += (double)c;
  }
#pragma unroll
  for (int off = 32; off > 0; off >>= 1) {
    d_st += __shfl_down(d_st, off);
    d_ch += __shfl_down(d_ch, off);
  }
  if (lane == 0) {
    dst[row] = d_st * (1.0 / D_DIM);
    dch[row] = d_ch * (1.0 / D_DIM);
  }
}

// ---------------------------------------------------------------------------
// Kernel 2: per-batch-row gate (f64) + exact top-k mask via MSB-first
// radix-select on distinct u64 keys.  (byte-identical to round 3 — known
// good; clean A/B on kernel 1 only.)
//   key = bits(g) with low 13 mantissa bits replaced by (T-1-i):
//   g>0 so the double bit pattern is order-preserving as u64; keys are all
//   distinct and lower index wins ties (matches jax.lax.top_k), so
//   "key >= kth-largest-key" selects exactly K elements.
// ---------------------------------------------------------------------------
__global__ __launch_bounds__(1024) void topk_kernel(
    const double* __restrict__ dst, const double* __restrict__ dch,
    const float* __restrict__ o_ce_p, const float* __restrict__ m_cu_p,
    const float* __restrict__ b_ce_p, const float* __restrict__ b_cu_p,
    float* __restrict__ g_out, float* __restrict__ mask_out) {
  const int b = blockIdx.x;
  const int tid = threadIdx.x;
  const int lane = tid & 63;
  const int wid = tid >> 6;

  __shared__ double wsum[16];
  __shared__ unsigned long long wmin[16], wmax[16];
  __shared__ unsigned hist[256];
  __shared__ unsigned bc_d, bc_cnt, bc_r;
  __shared__ unsigned long long bc_key;

  // ---- global mean of D_st (deterministic, identical in all blocks) ----
  double s = 0.0;
  for (int j = 0; j < N_ROWS / 1024; ++j) s += dst[j * 1024 + tid];
#pragma unroll
  for (int off = 32; off > 0; off >>= 1) s += __shfl_down(s, off);
  if (lane == 0) wsum[wid] = s;
  __syncthreads();
  double tot = 0.0;
#pragma unroll
  for (int w = 0; w < 16; ++w) tot += wsum[w];
  const double ma = tot * (1.0 / N_ROWS);

  // ---- scalars (f64) ----
  const double log_oce = log((double)(*o_ce_p) + EPS_D);
  const double mcu = (double)(*m_cu_p);
  double x = (double)(*b_ce_p);
  const double bce = (x > 30.0) ? x : log1p(exp(x)); // softplus
  x = (double)(*b_cu_p);
  const double bcu = (x > 30.0) ? x : log1p(exp(x));

  // ---- gate + keys (8 per thread, registers only) ----
  const double* dr = dst + (size_t)b * T_DIM;
  const double* cr = dch + (size_t)b * T_DIM;
  unsigned long long key[8];
  unsigned long long kmin = ~0ULL, kmax = 0ULL;
#pragma unroll
  for (int c = 0; c < 8; ++c) {
    const int i = c * 1024 + tid;
    const double CE = dr[i] - (cr[i] - log_oce);
    const double CU = dr[i] - mcu * ma;
    const double sce = 1.0 / (1.0 + exp(-bce * CE));
    const double scu = 1.0 / (1.0 + exp(-bcu * CU));
    const double g = sce + scu - sce * scu;
    g_out[(size_t)b * T_DIM + i] = (float)g;
    const unsigned long long ub = (unsigned long long)__double_as_longlong(g);
    const unsigned long long k =
        (ub & ~0x1FFFULL) | (unsigned long long)(T_DIM - 1 - i);
    key[c] = k;
    kmin = (k < kmin) ? k : kmin;
    kmax = (k > kmax) ? k : kmax;
  }
  // block min/max (uniform result in every thread)
#pragma unroll
  for (int off = 32; off > 0; off >>= 1) {
    unsigned long long tmin = __shfl_down(kmin, off);
    unsigned long long tmax = __shfl_down(kmax, off);
    kmin = (tmin < kmin) ? tmin : kmin;
    kmax = (tmax > kmax) ? tmax : kmax;
  }
  if (lane == 0) { wmin[wid] = kmin; wmax[wid] = kmax; }
  __syncthreads();
  kmin = wmin[0];
  kmax = wmax[0];
#pragma unroll
  for (int w = 1; w < 16; ++w) {
    kmin = (wmin[w] < kmin) ? wmin[w] : kmin;
    kmax = (wmax[w] > kmax) ? wmax[w] : kmax;
  }

  // ---- radix select: k-th largest of 8192 distinct keys ----
  const unsigned long long diff = kmin ^ kmax; // != 0 (index bits distinct)
  const int hb = 63 - __clzll(diff);
  const int bi0 = hb >> 3; // first informative byte
  const int sh_top = (bi0 + 1) * 8;
  unsigned long long pmask = (sh_top >= 64) ? 0ULL : (~0ULL << sh_top);
  unsigned long long prefix = kmin & pmask;
  unsigned r = K_SEL; // 1-based rank from the top within candidates
  unsigned long long thresh = 0ULL;
  bool found = false;

  for (int bi = bi0; bi >= 0 && !found; --bi) {
    const int sh = bi * 8;
    if (tid < 256) hist[tid] = 0;
    __syncthreads();
#pragma unroll
    for (int c = 0; c < 8; ++c)
      if ((key[c] & pmask) == prefix)
        atomicAdd(&hist[(unsigned)((key[c] >> sh) & 0xFF)], 1u);
    __syncthreads();
    if (wid == 0) {
      // lane holds bins {lane, 64+lane, 128+lane, 192+lane}
      unsigned h[4], S[4];
#pragma unroll
      for (int j = 0; j < 4; ++j) {
        h[j] = hist[j * 64 + lane];
        unsigned t = h[j];
#pragma unroll
        for (int off = 32; off > 0; off >>= 1) t += __shfl_xor(t, off);
        S[j] = t; // chunk total, uniform across wave
      }
      // pick chunk scanning from the top
      int J;
      unsigned above;
      if (S[3] >= r) { J = 3; above = 0; }
      else if (S[3] + S[2] >= r) { J = 2; above = S[3]; }
      else if (S[3] + S[2] + S[1] >= r) { J = 1; above = S[3] + S[2]; }
      else { J = 0; above = S[3] + S[2] + S[1]; }
      const unsigned r_in = r - above;
      // inclusive suffix-sum over the 64 bins of chunk J
      unsigned v = h[J];
#pragma unroll
      for (int off = 1; off < 64; off <<= 1) {
        unsigned o = __shfl_down(v, off);
        if (lane + off < 64) v += o;
      }
      unsigned sufnext = __shfl_down(v, 1);
      if (lane == 63) sufnext = 0;
      if (v >= r_in && sufnext < r_in) { // exactly one lane
        bc_d = (unsigned)(J * 64 + lane);
        bc_cnt = h[J];
        bc_r = r_in - sufnext;
      }
    }
    __syncthreads();
    const unsigned d = bc_d;
    const unsigned cnt = bc_cnt;
    r = bc_r;
    prefix |= (unsigned long long)d << sh;
    pmask |= 0xFFULL << sh;
    if (cnt == 1) { // unique candidate == the k-th largest key
#pragma unroll
      for (int c = 0; c < 8; ++c)
        if ((key[c] & pmask) == prefix) bc_key = key[c];
      __syncthreads();
      thresh = bc_key;
      found = true;
    }
  }
  if (!found) thresh = prefix; // unreachable (keys distinct), safety net

  // ---- binary mask ----
#pragma unroll
  for (int c = 0; c < 8; ++c) {
    const int i = c * 1024 + tid;
    mask_out[(size_t)b * T_DIM + i] = (key[c] >= thresh) ? 1.0f : 0.0f;
  }
}

extern "C" void kernel_launch(void* const* d_in, const int* in_sizes, int n_in,
                              void* d_out, int out_size, void* d_ws, size_t ws_size,
                              hipStream_t stream) {
  const float* a = (const float*)d_in[0];    // actual_residual   [B,T,D]
  const float* p = (const float*)d_in[1];    // predicted_residual [B,T,D]
  const float* o_ce = (const float*)d_in[2]; // scalars
  const float* m_cu = (const float*)d_in[3];
  const float* b_ce = (const float*)d_in[4];
  const float* b_cu = (const float*)d_in[5];
  float* out = (float*)d_out; // [0,65536): g_continuous, [65536,131072): mask

  // workspace: D_st[65536] | D_ch[65536]  (1 MiB, rewritten fully every call)
  double* dst = (double*)d_ws;
  double* dch = dst + N_ROWS;

  row_reduce_kernel<<<N_ROWS / 4, 256, 0, stream>>>(a, p, dst, dch);
  topk_kernel<<<B_DIM, 1024, 0, stream>>>(dst, dch, o_ce, m_cu, b_ce, b_cu,
                                          out, out + N_ROWS);
}

// Round 6
// 187.155 us; speedup vs baseline: 1.8445x; 1.0334x over previous
//
#include <hip/hip_runtime.h>
#include <math.h>

#define B_DIM 8
#define T_DIM 8192
#define D_DIM 2048
#define N_ROWS (B_DIM * T_DIM)
#define N_BLK (N_ROWS / 4) /* row_reduce blocks = 16384 */
#define K_SEL 2048         /* max(1, int(T_DIM * 0.25)) */
#define EPS_D 1e-10

typedef float f32x4 __attribute__((ext_vector_type(4))); // clang vector: valid
                                                         // for nontemporal_load

// ---------------------------------------------------------------------------
// Kernel 1: per-row squared-norm reductions.  One WAVE per (b,t) row
// (4 rows per 256-thread block).  All 16 float4 loads issued before any math
// (max loads in flight); nontemporal (1 GB stream can't live in 32 MiB L2).
// v6: additionally emits one deterministic per-block partial sum of the 4
// rows' D_st (fixed wave order) so topk's mean scan shrinks 4x.
// Math order bit-identical to round 5.
// ---------------------------------------------------------------------------
__global__ __launch_bounds__(256) void row_reduce_kernel(
    const float* __restrict__ a, const float* __restrict__ p,
    double* __restrict__ dst, double* __restrict__ dch,
    double* __restrict__ bsum) {
  const int tid = threadIdx.x;
  const int lane = tid & 63;
  const int wid = tid >> 6;
  const int row = blockIdx.x * 4 + wid;
  const f32x4* a4 = reinterpret_cast<const f32x4*>(a) + (size_t)row * (D_DIM / 4);
  const f32x4* p4 = reinterpret_cast<const f32x4*>(p) + (size_t)row * (D_DIM / 4);

  f32x4 av[8], pv[8];
#pragma unroll
  for (int it = 0; it < 8; ++it)
    av[it] = __builtin_nontemporal_load(&a4[it * 64 + lane]);
#pragma unroll
  for (int it = 0; it < 8; ++it)
    pv[it] = __builtin_nontemporal_load(&p4[it * 64 + lane]);

  double d_st = 0.0, d_ch = 0.0;
#pragma unroll
  for (int it = 0; it < 8; ++it) {
    float s = av[it].x * av[it].x;
    s = fmaf(av[it].y, av[it].y, s);
    s = fmaf(av[it].z, av[it].z, s);
    s = fmaf(av[it].w, av[it].w, s);
    float dx = av[it].x - pv[it].x, dy = av[it].y - pv[it].y;
    float dz = av[it].z - pv[it].z, dw = av[it].w - pv[it].w;
    float c = dx * dx;
    c = fmaf(dy, dy, c);
    c = fmaf(dz, dz, c);
    c = fmaf(dw, dw, c);
    d_st += (double)s;
    d_ch += (double)c;
  }
#pragma unroll
  for (int off = 32; off > 0; off >>= 1) {
    d_st += __shfl_down(d_st, off);
    d_ch += __shfl_down(d_ch, off);
  }
  __shared__ double part[4];
  if (lane == 0) {
    const double v_st = d_st * (1.0 / D_DIM);
    dst[row] = v_st;
    dch[row] = d_ch * (1.0 / D_DIM);
    part[wid] = v_st;
  }
  __syncthreads();
  if (tid == 0)
    bsum[blockIdx.x] = ((part[0] + part[1]) + part[2]) + part[3]; // fixed order
}

// ---------------------------------------------------------------------------
// Kernel 2: per-batch-row gate (f64) + exact top-k mask via MSB-first
// radix-select on distinct u64 keys.
//   key = bits(g) with low 13 mantissa bits replaced by (T-1-i):
//   g>0 so the double bit pattern is order-preserving as u64; keys are all
//   distinct and lower index wins ties (matches jax.lax.top_k), so
//   "key >= kth-largest-key" selects exactly K elements.
// v6: global mean now reduces the 16384 per-block partials (128 KB) instead
// of 65536 D_st values (512 KB) — deterministic fixed-order tree, identical
// in every block.
// ---------------------------------------------------------------------------
__global__ __launch_bounds__(1024) void topk_kernel(
    const double* __restrict__ dst, const double* __restrict__ dch,
    const double* __restrict__ bsum,
    const float* __restrict__ o_ce_p, const float* __restrict__ m_cu_p,
    const float* __restrict__ b_ce_p, const float* __restrict__ b_cu_p,
    float* __restrict__ g_out, float* __restrict__ mask_out) {
  const int b = blockIdx.x;
  const int tid = threadIdx.x;
  const int lane = tid & 63;
  const int wid = tid >> 6;

  __shared__ double wsum[16];
  __shared__ unsigned long long wmin[16], wmax[16];
  __shared__ unsigned hist[256];
  __shared__ unsigned bc_d, bc_cnt, bc_r;
  __shared__ unsigned long long bc_key;

  // ---- global mean of D_st from per-block partials (deterministic) ----
  double s = 0.0;
#pragma unroll
  for (int j = 0; j < N_BLK / 1024; ++j) s += bsum[j * 1024 + tid];
#pragma unroll
  for (int off = 32; off > 0; off >>= 1) s += __shfl_down(s, off);
  if (lane == 0) wsum[wid] = s;
  __syncthreads();
  double tot = 0.0;
#pragma unroll
  for (int w = 0; w < 16; ++w) tot += wsum[w];
  const double ma = tot * (1.0 / N_ROWS);

  // ---- scalars (f64) ----
  const double log_oce = log((double)(*o_ce_p) + EPS_D);
  const double mcu = (double)(*m_cu_p);
  double x = (double)(*b_ce_p);
  const double bce = (x > 30.0) ? x : log1p(exp(x)); // softplus
  x = (double)(*b_cu_p);
  const double bcu = (x > 30.0) ? x : log1p(exp(x));

  // ---- gate + keys (8 per thread, registers only) ----
  const double* dr = dst + (size_t)b * T_DIM;
  const double* cr = dch + (size_t)b * T_DIM;
  unsigned long long key[8];
  unsigned long long kmin = ~0ULL, kmax = 0ULL;
#pragma unroll
  for (int c = 0; c < 8; ++c) {
    const int i = c * 1024 + tid;
    const double CE = dr[i] - (cr[i] - log_oce);
    const double CU = dr[i] - mcu * ma;
    const double sce = 1.0 / (1.0 + exp(-bce * CE));
    const double scu = 1.0 / (1.0 + exp(-bcu * CU));
    const double g = sce + scu - sce * scu;
    g_out[(size_t)b * T_DIM + i] = (float)g;
    const unsigned long long ub = (unsigned long long)__double_as_longlong(g);
    const unsigned long long k =
        (ub & ~0x1FFFULL) | (unsigned long long)(T_DIM - 1 - i);
    key[c] = k;
    kmin = (k < kmin) ? k : kmin;
    kmax = (k > kmax) ? k : kmax;
  }
  // block min/max (uniform result in every thread)
#pragma unroll
  for (int off = 32; off > 0; off >>= 1) {
    unsigned long long tmin = __shfl_down(kmin, off);
    unsigned long long tmax = __shfl_down(kmax, off);
    kmin = (tmin < kmin) ? tmin : kmin;
    kmax = (tmax > kmax) ? tmax : kmax;
  }
  if (lane == 0) { wmin[wid] = kmin; wmax[wid] = kmax; }
  __syncthreads();
  kmin = wmin[0];
  kmax = wmax[0];
#pragma unroll
  for (int w = 1; w < 16; ++w) {
    kmin = (wmin[w] < kmin) ? wmin[w] : kmin;
    kmax = (wmax[w] > kmax) ? wmax[w] : kmax;
  }

  // ---- radix select: k-th largest of 8192 distinct keys ----
  const unsigned long long diff = kmin ^ kmax; // != 0 (index bits distinct)
  const int hb = 63 - __clzll(diff);
  const int bi0 = hb >> 3; // first informative byte
  const int sh_top = (bi0 + 1) * 8;
  unsigned long long pmask = (sh_top >= 64) ? 0ULL : (~0ULL << sh_top);
  unsigned long long prefix = kmin & pmask;
  unsigned r = K_SEL; // 1-based rank from the top within candidates
  unsigned long long thresh = 0ULL;
  bool found = false;

  for (int bi = bi0; bi >= 0 && !found; --bi) {
    const int sh = bi * 8;
    if (tid < 256) hist[tid] = 0;
    __syncthreads();
#pragma unroll
    for (int c = 0; c < 8; ++c)
      if ((key[c] & pmask) == prefix)
        atomicAdd(&hist[(unsigned)((key[c] >> sh) & 0xFF)], 1u);
    __syncthreads();
    if (wid == 0) {
      // lane holds bins {lane, 64+lane, 128+lane, 192+lane}
      unsigned h[4], S[4];
#pragma unroll
      for (int j = 0; j < 4; ++j) {
        h[j] = hist[j * 64 + lane];
        unsigned t = h[j];
#pragma unroll
        for (int off = 32; off > 0; off >>= 1) t += __shfl_xor(t, off);
        S[j] = t; // chunk total, uniform across wave
      }
      // pick chunk scanning from the top
      int J;
      unsigned above;
      if (S[3] >= r) { J = 3; above = 0; }
      else if (S[3] + S[2] >= r) { J = 2; above = S[3]; }
      else if (S[3] + S[2] + S[1] >= r) { J = 1; above = S[3] + S[2]; }
      else { J = 0; above = S[3] + S[2] + S[1]; }
      const unsigned r_in = r - above;
      // inclusive suffix-sum over the 64 bins of chunk J
      unsigned v = h[J];
#pragma unroll
      for (int off = 1; off < 64; off <<= 1) {
        unsigned o = __shfl_down(v, off);
        if (lane + off < 64) v += o;
      }
      unsigned sufnext = __shfl_down(v, 1);
      if (lane == 63) sufnext = 0;
      if (v >= r_in && sufnext < r_in) { // exactly one lane
        bc_d = (unsigned)(J * 64 + lane);
        bc_cnt = h[J];
        bc_r = r_in - sufnext;
      }
    }
    __syncthreads();
    const unsigned d = bc_d;
    const unsigned cnt = bc_cnt;
    r = bc_r;
    prefix |= (unsigned long long)d << sh;
    pmask |= 0xFFULL << sh;
    if (cnt == 1) { // unique candidate == the k-th largest key
#pragma unroll
      for (int c = 0; c < 8; ++c)
        if ((key[c] & pmask) == prefix) bc_key = key[c];
      __syncthreads();
      thresh = bc_key;
      found = true;
    }
  }
  if (!found) thresh = prefix; // unreachable (keys distinct), safety net

  // ---- binary mask ----
#pragma unroll
  for (int c = 0; c < 8; ++c) {
    const int i = c * 1024 + tid;
    mask_out[(size_t)b * T_DIM + i] = (key[c] >= thresh) ? 1.0f : 0.0f;
  }
}

extern "C" void kernel_launch(void* const* d_in, const int* in_sizes, int n_in,
                              void* d_out, int out_size, void* d_ws, size_t ws_size,
                              hipStream_t stream) {
  const float* a = (const float*)d_in[0];    // actual_residual   [B,T,D]
  const float* p = (const float*)d_in[1];    // predicted_residual [B,T,D]
  const float* o_ce = (const float*)d_in[2]; // scalars
  const float* m_cu = (const float*)d_in[3];
  const float* b_ce = (const float*)d_in[4];
  const float* b_cu = (const float*)d_in[5];
  float* out = (float*)d_out; // [0,65536): g_continuous, [65536,131072): mask

  // workspace: D_st[65536] | D_ch[65536] | bsum[16384]  (1.125 MiB)
  double* dst = (double*)d_ws;
  double* dch = dst + N_ROWS;
  double* bsum = dch + N_ROWS;

  row_reduce_kernel<<<N_BLK, 256, 0, stream>>>(a, p, dst, dch, bsum);
  topk_kernel<<<B_DIM, 1024, 0, stream>>>(dst, dch, bsum, o_ce, m_cu, b_ce,
                                          b_cu, out, out + N_ROWS);
}